// Round 2
// baseline (569.605 us; speedup 1.0000x reference)
//
#include <hip/hip_runtime.h>
#include <cstdint>

// ---------------------------------------------------------------------------
// SAGAN self-attention block, bf16-MFMA pipeline.
// All GEMMs are NT form: C[m,n] = sum_k Arow[m][k] * Brow[n][k]
//   (A: [M,K] row-major, B: [N,K] row-major), m97-style 128x128 tile, BK=32.
// ---------------------------------------------------------------------------

typedef short s8v __attribute__((ext_vector_type(8)));   // 8 bf16 bits (4 VGPR)
typedef float f32x4 __attribute__((ext_vector_type(4)));

#define DEVI static __device__ __forceinline__

DEVI unsigned short f2bf(float f) {
  union { float f; uint32_t u; } x; x.f = f;
  uint32_t u = x.u;
  return (unsigned short)((u + 0x7fffu + ((u >> 16) & 1u)) >> 16);  // RNE
}

DEVI void gl_lds16(const void* g, void* l) {
  // async global->LDS, 16B per lane; LDS dest must be wave-uniform base.
  __builtin_amdgcn_global_load_lds(
      (const __attribute__((address_space(1))) void*)g,
      (__attribute__((address_space(3))) void*)l,
      16, 0, 0);
}

// ---------------------------------------------------------------------------
// NT GEMM: 128x128 tile, 4 waves (2x2), each wave 64x64 = 4x4 frags of
// 16x16x32 bf16 MFMA. Epilogue templated:
//   OBF: 1 -> bf16 out, 0 -> fp32 out
//   BIAS: 0 none, 1 bias[row(m)], 2 bias[col(n)]
//   PEM:  0 none, 1 +pe[row*4096+col], 2 +pe[col*4096+row]
//   SILU: apply x*sigmoid(x)
// ---------------------------------------------------------------------------
template <int OBF, int BIAS, int PEM, int SILU>
__global__ __launch_bounds__(256) void gemm_nt(
    const unsigned short* __restrict__ A, const unsigned short* __restrict__ B,
    void* __restrict__ Cp, int K, int N, long sA, long sB, long sC,
    const float* __restrict__ bias, const float* __restrict__ pe, float scale) {
  const int bz = blockIdx.z;
  const unsigned short* Ab = A + (long)bz * sA;
  const unsigned short* Bb = B + (long)bz * sB;
  const int m0 = blockIdx.x * 128, n0 = blockIdx.y * 128;
  __shared__ __align__(16) unsigned short As[4096], Bs[4096];  // [128][32]
  const int t = threadIdx.x;
  const int wave = t >> 6, lane = t & 63;
  const int wr = wave >> 1, wc = wave & 1;

  f32x4 acc[4][4];
#pragma unroll
  for (int i = 0; i < 4; i++)
#pragma unroll
    for (int j = 0; j < 4; j++) acc[i][j] = f32x4{0.f, 0.f, 0.f, 0.f};

  const int srow = t >> 2;          // 0..63 tile row per 16B chunk
  const int scol = (t & 3) * 8;     // 0,8,16,24 (bf16 elements)
  unsigned short* lA = As + wave * 512;  // wave-uniform LDS base
  unsigned short* lB = Bs + wave * 512;
  const int rl = lane & 15, kp = (lane >> 4) * 8;

  for (int k0 = 0; k0 < K; k0 += 32) {
    gl_lds16(Ab + (long)(m0 + srow) * K + k0 + scol, lA);
    gl_lds16(Ab + (long)(m0 + 64 + srow) * K + k0 + scol, lA + 2048);
    gl_lds16(Bb + (long)(n0 + srow) * K + k0 + scol, lB);
    gl_lds16(Bb + (long)(n0 + 64 + srow) * K + k0 + scol, lB + 2048);
    __syncthreads();  // drains vmcnt before barrier -> LDS valid

    s8v af[4], bfr[4];
#pragma unroll
    for (int i = 0; i < 4; i++)
      af[i] = *(const s8v*)(As + (wr * 64 + i * 16 + rl) * 32 + kp);
#pragma unroll
    for (int j = 0; j < 4; j++)
      bfr[j] = *(const s8v*)(Bs + (wc * 64 + j * 16 + rl) * 32 + kp);
#pragma unroll
    for (int i = 0; i < 4; i++)
#pragma unroll
      for (int j = 0; j < 4; j++)
        acc[i][j] = __builtin_amdgcn_mfma_f32_16x16x32_bf16(af[i], bfr[j],
                                                            acc[i][j], 0, 0, 0);
    __syncthreads();
  }

  // C/D layout (m89-verified): col = lane&15, row = (lane>>4)*4 + r
  const long cb = (long)bz * sC;
#pragma unroll
  for (int i = 0; i < 4; i++) {
    const int r0 = m0 + wr * 64 + i * 16 + (lane >> 4) * 4;
#pragma unroll
    for (int j = 0; j < 4; j++) {
      const int col = n0 + wc * 64 + j * 16 + (lane & 15);
#pragma unroll
      for (int r = 0; r < 4; r++) {
        const int row = r0 + r;
        float val = acc[i][j][r] * scale;
        if (BIAS == 1) val += bias[row];
        if (BIAS == 2) val += bias[col];
        if (PEM == 1) val += pe[(long)row * 4096 + col];
        if (PEM == 2) val += pe[(long)col * 4096 + row];
        if (SILU) val = val / (1.0f + __expf(-val));
        const long ci = cb + (long)row * N + col;
        if (OBF)
          ((unsigned short*)Cp)[ci] = f2bf(val);
        else
          ((float*)Cp)[ci] = val;
      }
    }
  }
}

// Convert the six 256x256 fp32 weight matrices to bf16 (contiguous dst).
__global__ __launch_bounds__(256) void convert6(
    const float* __restrict__ a0, const float* __restrict__ a1,
    const float* __restrict__ a2, const float* __restrict__ a3,
    const float* __restrict__ a4, const float* __restrict__ a5,
    unsigned short* __restrict__ dst) {
  int idx = blockIdx.x * 256 + threadIdx.x;
  int m = idx >> 16, r = idx & 65535;
  const float* s;
  switch (m) {
    case 0: s = a0; break;
    case 1: s = a1; break;
    case 2: s = a2; break;
    case 3: s = a3; break;
    case 4: s = a4; break;
    default: s = a5; break;
  }
  dst[idx] = f2bf(s[r]);
}

// Sinusoidal table: embed[t,d] = sin/cos(t * 10000^(-d/128)), d even->sin.
__global__ __launch_bounds__(256) void embed_k(unsigned short* __restrict__ e) {
  int idx = blockIdx.x * 256 + threadIdx.x;
  int t = idx >> 8, d = idx & 255;
  float freq = powf(10000.0f, -(float)d * (1.0f / 128.0f));
  float w = (float)t * freq;
  float r = (d & 1) ? cosf(w) : sinf(w);
  e[idx] = f2bf(r);
}

// x [4][256][4096] fp32  ->  XT [4][4096][256] bf16
__global__ void transpose_x(const float* __restrict__ x,
                            unsigned short* __restrict__ xt) {
  __shared__ float tile[32][33];
  const int b = blockIdx.z;
  const int s0 = blockIdx.x * 32, c0 = blockIdx.y * 32;
  const int tx = threadIdx.x, ty = threadIdx.y;
  const float* xb = x + (long)b * 256 * 4096;
#pragma unroll
  for (int r = 0; r < 32; r += 8)
    tile[ty + r][tx] = xb[(long)(c0 + ty + r) * 4096 + s0 + tx];
  __syncthreads();
  unsigned short* xtb = xt + (long)b * 4096 * 256;
#pragma unroll
  for (int r = 0; r < 32; r += 8)
    xtb[(long)(s0 + ty + r) * 256 + c0 + tx] = f2bf(tile[tx][ty + r]);
}

// Row softmax of logitsT [4096][4096] fp32 -> P bf16 (same layout).
__global__ __launch_bounds__(256) void softmax_rows(
    const float* __restrict__ Lg, unsigned short* __restrict__ P) {
  const int j = blockIdx.x;
  const float4* row = (const float4*)(Lg + (long)j * 4096);
  const int t = threadIdx.x;
  float4 v[4];
  v[0] = row[t]; v[1] = row[t + 256]; v[2] = row[t + 512]; v[3] = row[t + 768];
  float m = -3.4e38f;
#pragma unroll
  for (int i = 0; i < 4; i++)
    m = fmaxf(m, fmaxf(fmaxf(v[i].x, v[i].y), fmaxf(v[i].z, v[i].w)));
#pragma unroll
  for (int o = 32; o; o >>= 1) m = fmaxf(m, __shfl_xor(m, o));
  __shared__ float rmax[4], rsum[4];
  const int wave = t >> 6, lane = t & 63;
  if (lane == 0) rmax[wave] = m;
  __syncthreads();
  m = fmaxf(fmaxf(rmax[0], rmax[1]), fmaxf(rmax[2], rmax[3]));
  float s = 0.f;
  float e[16];
#pragma unroll
  for (int i = 0; i < 4; i++) {
    e[i * 4 + 0] = __expf(v[i].x - m);
    e[i * 4 + 1] = __expf(v[i].y - m);
    e[i * 4 + 2] = __expf(v[i].z - m);
    e[i * 4 + 3] = __expf(v[i].w - m);
    s += e[i * 4 + 0] + e[i * 4 + 1] + e[i * 4 + 2] + e[i * 4 + 3];
  }
#pragma unroll
  for (int o = 32; o; o >>= 1) s += __shfl_xor(s, o);
  if (lane == 0) rsum[wave] = s;
  __syncthreads();
  s = rsum[0] + rsum[1] + rsum[2] + rsum[3];
  const float inv = 1.0f / s;
  ushort4* prow = (ushort4*)(P + (long)j * 4096);
#pragma unroll
  for (int i = 0; i < 4; i++) {
    ushort4 pk;
    pk.x = f2bf(e[i * 4 + 0] * inv);
    pk.y = f2bf(e[i * 4 + 1] * inv);
    pk.z = f2bf(e[i * 4 + 2] * inv);
    pk.w = f2bf(e[i * 4 + 3] * inv);
    prow[t + i * 256] = pk;
  }
}

// ---------------------------------------------------------------------------
extern "C" void kernel_launch(void* const* d_in, const int* in_sizes, int n_in,
                              void* d_out, int out_size, void* d_ws,
                              size_t ws_size, hipStream_t stream) {
  const float* x  = (const float*)d_in[0];
  const float* wq = (const float*)d_in[1];
  const float* bq = (const float*)d_in[2];
  const float* wk = (const float*)d_in[3];
  const float* bk = (const float*)d_in[4];
  const float* wv = (const float*)d_in[5];
  const float* bv = (const float*)d_in[6];
  const float* wo = (const float*)d_in[7];
  const float* bo = (const float*)d_in[8];
  const float* w1 = (const float*)d_in[9];
  const float* b1 = (const float*)d_in[10];
  const float* w2 = (const float*)d_in[11];
  const float* b2 = (const float*)d_in[12];
  float* out = (float*)d_out;

  char* ws = (char*)d_ws;
  unsigned short* wqb = (unsigned short*)(ws + 0);         // 6x 256x256 bf16
  unsigned short* wkb = (unsigned short*)(ws + 131072);
  unsigned short* wvb = (unsigned short*)(ws + 262144);
  unsigned short* wob = (unsigned short*)(ws + 393216);
  unsigned short* w1b = (unsigned short*)(ws + 524288);
  unsigned short* w2b = (unsigned short*)(ws + 655360);
  unsigned short* emb = (unsigned short*)(ws + 786432);    // [4096][256] bf16
  unsigned short* h1b = (unsigned short*)(ws + 2883584);   // [4096][256] bf16
  float*          peF = (float*)(ws + 4980736);            // [4096][256] fp32
  unsigned short* XT  = (unsigned short*)(ws + 9175040);   // [4][4096][256]
  unsigned short* qT  = (unsigned short*)(ws + 17563648);  // [4][4096][256]
  unsigned short* kT  = (unsigned short*)(ws + 25952256);  // [4][4096][256]
  unsigned short* vB  = (unsigned short*)(ws + 34340864);  // [4][256][4096]
  unsigned short* rT  = (unsigned short*)(ws + 42729472);  // [4][4096][256]
  float*          lg  = (float*)(ws + 51118080);           // [4096][4096] fp32
  unsigned short* P   = (unsigned short*)(ws + 118226944); // [4096][4096] bf16
  (void)ws_size; (void)in_sizes; (void)n_in; (void)out_size;

  const dim3 B256(256);
  const long S = 1048576;  // 4096*256 (= 256*4096) element batch stride

  convert6<<<1536, B256, 0, stream>>>(wq, wk, wv, wo, w1, w2, wqb);
  embed_k<<<4096, B256, 0, stream>>>(emb);
  // pe MLP: h1 = silu(embed @ w1^T + b1); peF = h1 @ w2^T + b2  (fp32 out)
  gemm_nt<1, 2, 0, 1><<<dim3(32, 2, 1), B256, 0, stream>>>(
      emb, w1b, h1b, 256, 256, 0, 0, 0, b1, nullptr, 1.0f);
  gemm_nt<0, 2, 0, 0><<<dim3(32, 2, 1), B256, 0, stream>>>(
      h1b, w2b, peF, 256, 256, 0, 0, 0, b2, nullptr, 1.0f);
  transpose_x<<<dim3(128, 8, 4), dim3(32, 8), 0, stream>>>(x, XT);
  // qT[s,o] = XT.wq + bq[o] + pe[o*4096+s]   (pe mode 2: col-major index)
  gemm_nt<1, 2, 2, 0><<<dim3(32, 2, 4), B256, 0, stream>>>(
      XT, wqb, qT, 256, 256, S, 0, S, bq, peF, 1.0f);
  gemm_nt<1, 2, 2, 0><<<dim3(32, 2, 4), B256, 0, stream>>>(
      XT, wkb, kT, 256, 256, S, 0, S, bk, peF, 1.0f);
  // v[o,s] = wv.XT + bv[o] + pe[o*4096+s]    (pe mode 1: row-major index)
  gemm_nt<1, 1, 1, 0><<<dim3(2, 32, 4), B256, 0, stream>>>(
      wvb, XT, vB, 256, 4096, 0, S, S, bv, peF, 1.0f);

  for (int b = 0; b < 4; ++b) {
    // logitsT[j,i] = kT[j].qT[i] / 16  (fp32)
    gemm_nt<0, 0, 0, 0><<<dim3(32, 32, 1), B256, 0, stream>>>(
        kT + (long)b * S, qT + (long)b * S, lg, 256, 4096, 0, 0, 0,
        nullptr, nullptr, 0.0625f);
    softmax_rows<<<4096, B256, 0, stream>>>(lg, P);
    // resT[j,c] = sum_i P[j,i] v[c,i]
    gemm_nt<1, 0, 0, 0><<<dim3(32, 2, 1), B256, 0, stream>>>(
        P, vB + (long)b * S, rT + (long)b * S, 4096, 256, 0, 0, 0,
        nullptr, nullptr, 1.0f);
  }
  // out[o,s] = wout . resT + b_out[o]  (fp32 -> d_out)
  gemm_nt<0, 1, 0, 0><<<dim3(2, 32, 4), B256, 0, stream>>>(
      wob, rT, out, 256, 4096, 0, S, S, bo, nullptr, 1.0f);
}

// Round 3
// 334.002 us; speedup vs baseline: 1.7054x; 1.7054x over previous
//
#include <hip/hip_runtime.h>
#include <cstdint>

// ---------------------------------------------------------------------------
// SAGAN self-attention block, bf16-MFMA pipeline.
// All GEMMs are NT form: C[m,n] = sum_k Arow[m][k] * Brow[n][k]
//   (A: [M,K] row-major, B: [N,K] row-major), m97-style 128x128 tile, BK=32.
// Split-K supported via (ld != K) + sA/sB used as per-z k-offsets.
// ---------------------------------------------------------------------------

typedef short s8v __attribute__((ext_vector_type(8)));   // 8 bf16 bits (4 VGPR)
typedef float f32x4 __attribute__((ext_vector_type(4)));

#define DEVI static __device__ __forceinline__

DEVI unsigned short f2bf(float f) {
  union { float f; uint32_t u; } x; x.f = f;
  uint32_t u = x.u;
  return (unsigned short)((u + 0x7fffu + ((u >> 16) & 1u)) >> 16);  // RNE
}

DEVI void gl_lds16(const void* g, void* l) {
  // async global->LDS, 16B per lane; LDS dest must be wave-uniform base.
  __builtin_amdgcn_global_load_lds(
      (const __attribute__((address_space(1))) void*)g,
      (__attribute__((address_space(3))) void*)l,
      16, 0, 0);
}

// ---------------------------------------------------------------------------
// NT GEMM: 128x128 tile, 4 waves (2x2), each wave 64x64 = 4x4 frags of
// 16x16x32 bf16 MFMA. Epilogue templated:
//   OBF: 1 -> bf16 out, 0 -> fp32 out
//   BIAS: 0 none, 1 bias[row(m)], 2 bias[col(n)]
//   PEM:  0 none, 1 +pe[row*4096+col], 2 +pe[col*4096+row]
//   SILU: apply x*sigmoid(x)
// K = k-loop length; ld = row stride of A and B (== K unless split-K).
// ---------------------------------------------------------------------------
template <int OBF, int BIAS, int PEM, int SILU>
__global__ __launch_bounds__(256) void gemm_nt(
    const unsigned short* __restrict__ A, const unsigned short* __restrict__ B,
    void* __restrict__ Cp, int K, int N, int ld, long sA, long sB, long sC,
    const float* __restrict__ bias, const float* __restrict__ pe, float scale) {
  const int bz = blockIdx.z;
  const unsigned short* Ab = A + (long)bz * sA;
  const unsigned short* Bb = B + (long)bz * sB;
  const int m0 = blockIdx.x * 128, n0 = blockIdx.y * 128;
  __shared__ __align__(16) unsigned short As[4096], Bs[4096];  // [128][32]
  const int t = threadIdx.x;
  const int wave = t >> 6, lane = t & 63;
  const int wr = wave >> 1, wc = wave & 1;

  f32x4 acc[4][4];
#pragma unroll
  for (int i = 0; i < 4; i++)
#pragma unroll
    for (int j = 0; j < 4; j++) acc[i][j] = f32x4{0.f, 0.f, 0.f, 0.f};

  const int srow = t >> 2;          // 0..63 tile row per 16B chunk
  const int scol = (t & 3) * 8;     // 0,8,16,24 (bf16 elements)
  unsigned short* lA = As + wave * 512;  // wave-uniform LDS base
  unsigned short* lB = Bs + wave * 512;
  const int rl = lane & 15, kp = (lane >> 4) * 8;

  for (int k0 = 0; k0 < K; k0 += 32) {
    gl_lds16(Ab + (long)(m0 + srow) * ld + k0 + scol, lA);
    gl_lds16(Ab + (long)(m0 + 64 + srow) * ld + k0 + scol, lA + 2048);
    gl_lds16(Bb + (long)(n0 + srow) * ld + k0 + scol, lB);
    gl_lds16(Bb + (long)(n0 + 64 + srow) * ld + k0 + scol, lB + 2048);
    __syncthreads();  // drains vmcnt before barrier -> LDS valid

    s8v af[4], bfr[4];
#pragma unroll
    for (int i = 0; i < 4; i++)
      af[i] = *(const s8v*)(As + (wr * 64 + i * 16 + rl) * 32 + kp);
#pragma unroll
    for (int j = 0; j < 4; j++)
      bfr[j] = *(const s8v*)(Bs + (wc * 64 + j * 16 + rl) * 32 + kp);
#pragma unroll
    for (int i = 0; i < 4; i++)
#pragma unroll
      for (int j = 0; j < 4; j++)
        acc[i][j] = __builtin_amdgcn_mfma_f32_16x16x32_bf16(af[i], bfr[j],
                                                            acc[i][j], 0, 0, 0);
    __syncthreads();
  }

  // C/D layout (m89-verified): col = lane&15, row = (lane>>4)*4 + r
  const long cb = (long)bz * sC;
#pragma unroll
  for (int i = 0; i < 4; i++) {
    const int r0 = m0 + wr * 64 + i * 16 + (lane >> 4) * 4;
#pragma unroll
    for (int j = 0; j < 4; j++) {
      const int col = n0 + wc * 64 + j * 16 + (lane & 15);
#pragma unroll
      for (int r = 0; r < 4; r++) {
        const int row = r0 + r;
        float val = acc[i][j][r] * scale;
        if (BIAS == 1) val += bias[row];
        if (BIAS == 2) val += bias[col];
        if (PEM == 1) val += pe[(long)row * 4096 + col];
        if (PEM == 2) val += pe[(long)col * 4096 + row];
        if (SILU) val = val / (1.0f + __expf(-val));
        const long ci = cb + (long)row * N + col;
        if (OBF)
          ((unsigned short*)Cp)[ci] = f2bf(val);
        else
          ((float*)Cp)[ci] = val;
      }
    }
  }
}

// Sum 8 split-K fp32 partials [8][1048576] -> bf16 [1048576].
__global__ __launch_bounds__(256) void reduce8(
    const float* __restrict__ part, unsigned short* __restrict__ dst) {
  const int id = blockIdx.x * 256 + threadIdx.x;  // 0..262143 (float4 units)
  float4 a = ((const float4*)part)[id];
#pragma unroll
  for (int s = 1; s < 8; s++) {
    float4 p = ((const float4*)part)[s * 262144 + id];
    a.x += p.x; a.y += p.y; a.z += p.z; a.w += p.w;
  }
  ushort4 o;
  o.x = f2bf(a.x); o.y = f2bf(a.y); o.z = f2bf(a.z); o.w = f2bf(a.w);
  ((ushort4*)dst)[id] = o;
}

// Convert the six 256x256 fp32 weight matrices to bf16 (contiguous dst).
__global__ __launch_bounds__(256) void convert6(
    const float* __restrict__ a0, const float* __restrict__ a1,
    const float* __restrict__ a2, const float* __restrict__ a3,
    const float* __restrict__ a4, const float* __restrict__ a5,
    unsigned short* __restrict__ dst) {
  int idx = blockIdx.x * 256 + threadIdx.x;
  int m = idx >> 16, r = idx & 65535;
  const float* s;
  switch (m) {
    case 0: s = a0; break;
    case 1: s = a1; break;
    case 2: s = a2; break;
    case 3: s = a3; break;
    case 4: s = a4; break;
    default: s = a5; break;
  }
  dst[idx] = f2bf(s[r]);
}

// Sinusoidal table: embed[t,d] = sin/cos(t * 10000^(-d/128)), d even->sin.
__global__ __launch_bounds__(256) void embed_k(unsigned short* __restrict__ e) {
  int idx = blockIdx.x * 256 + threadIdx.x;
  int t = idx >> 8, d = idx & 255;
  float freq = powf(10000.0f, -(float)d * (1.0f / 128.0f));
  float w = (float)t * freq;
  float r = (d & 1) ? cosf(w) : sinf(w);
  e[idx] = f2bf(r);
}

// x [4][256][4096] fp32  ->  XT [4][4096][256] bf16
__global__ void transpose_x(const float* __restrict__ x,
                            unsigned short* __restrict__ xt) {
  __shared__ float tile[32][33];
  const int b = blockIdx.z;
  const int s0 = blockIdx.x * 32, c0 = blockIdx.y * 32;
  const int tx = threadIdx.x, ty = threadIdx.y;
  const float* xb = x + (long)b * 256 * 4096;
#pragma unroll
  for (int r = 0; r < 32; r += 8)
    tile[ty + r][tx] = xb[(long)(c0 + ty + r) * 4096 + s0 + tx];
  __syncthreads();
  unsigned short* xtb = xt + (long)b * 4096 * 256;
#pragma unroll
  for (int r = 0; r < 32; r += 8)
    xtb[(long)(s0 + ty + r) * 256 + c0 + tx] = f2bf(tile[tx][ty + r]);
}

// Row softmax of logitsT [4096][4096] fp32 -> P bf16 (same layout).
__global__ __launch_bounds__(256) void softmax_rows(
    const float* __restrict__ Lg, unsigned short* __restrict__ P) {
  const int j = blockIdx.x;
  const float4* row = (const float4*)(Lg + (long)j * 4096);
  const int t = threadIdx.x;
  float4 v[4];
  v[0] = row[t]; v[1] = row[t + 256]; v[2] = row[t + 512]; v[3] = row[t + 768];
  float m = -3.4e38f;
#pragma unroll
  for (int i = 0; i < 4; i++)
    m = fmaxf(m, fmaxf(fmaxf(v[i].x, v[i].y), fmaxf(v[i].z, v[i].w)));
#pragma unroll
  for (int o = 32; o; o >>= 1) m = fmaxf(m, __shfl_xor(m, o));
  __shared__ float rmax[4], rsum[4];
  const int wave = t >> 6, lane = t & 63;
  if (lane == 0) rmax[wave] = m;
  __syncthreads();
  m = fmaxf(fmaxf(rmax[0], rmax[1]), fmaxf(rmax[2], rmax[3]));
  float s = 0.f;
  float e[16];
#pragma unroll
  for (int i = 0; i < 4; i++) {
    e[i * 4 + 0] = __expf(v[i].x - m);
    e[i * 4 + 1] = __expf(v[i].y - m);
    e[i * 4 + 2] = __expf(v[i].z - m);
    e[i * 4 + 3] = __expf(v[i].w - m);
    s += e[i * 4 + 0] + e[i * 4 + 1] + e[i * 4 + 2] + e[i * 4 + 3];
  }
#pragma unroll
  for (int o = 32; o; o >>= 1) s += __shfl_xor(s, o);
  if (lane == 0) rsum[wave] = s;
  __syncthreads();
  s = rsum[0] + rsum[1] + rsum[2] + rsum[3];
  const float inv = 1.0f / s;
  ushort4* prow = (ushort4*)(P + (long)j * 4096);
#pragma unroll
  for (int i = 0; i < 4; i++) {
    ushort4 pk;
    pk.x = f2bf(e[i * 4 + 0] * inv);
    pk.y = f2bf(e[i * 4 + 1] * inv);
    pk.z = f2bf(e[i * 4 + 2] * inv);
    pk.w = f2bf(e[i * 4 + 3] * inv);
    prow[t + i * 256] = pk;
  }
}

// ---------------------------------------------------------------------------
extern "C" void kernel_launch(void* const* d_in, const int* in_sizes, int n_in,
                              void* d_out, int out_size, void* d_ws,
                              size_t ws_size, hipStream_t stream) {
  const float* x  = (const float*)d_in[0];
  const float* wq = (const float*)d_in[1];
  const float* bq = (const float*)d_in[2];
  const float* wk = (const float*)d_in[3];
  const float* bk = (const float*)d_in[4];
  const float* wv = (const float*)d_in[5];
  const float* bv = (const float*)d_in[6];
  const float* wo = (const float*)d_in[7];
  const float* bo = (const float*)d_in[8];
  const float* w1 = (const float*)d_in[9];
  const float* b1 = (const float*)d_in[10];
  const float* w2 = (const float*)d_in[11];
  const float* b2 = (const float*)d_in[12];
  float* out = (float*)d_out;

  char* ws = (char*)d_ws;
  unsigned short* wqb = (unsigned short*)(ws + 0);         // 6x 256x256 bf16
  unsigned short* wkb = (unsigned short*)(ws + 131072);
  unsigned short* wvb = (unsigned short*)(ws + 262144);
  unsigned short* wob = (unsigned short*)(ws + 393216);
  unsigned short* w1b = (unsigned short*)(ws + 524288);
  unsigned short* w2b = (unsigned short*)(ws + 655360);
  unsigned short* emb = (unsigned short*)(ws + 786432);    // [4096][256] bf16
  unsigned short* h1b = (unsigned short*)(ws + 2883584);   // [4096][256] bf16
  float*          peF = (float*)(ws + 4980736);            // [4096][256] fp32
  unsigned short* XT  = (unsigned short*)(ws + 9175040);   // [4][4096][256]
  unsigned short* qT  = (unsigned short*)(ws + 17563648);  // [4][4096][256]
  unsigned short* kT  = (unsigned short*)(ws + 25952256);  // [4][4096][256]
  unsigned short* vB  = (unsigned short*)(ws + 34340864);  // [4][256][4096]
  unsigned short* rT  = (unsigned short*)(ws + 42729472);  // [4][4096][256]
  float*          lg  = (float*)(ws + 51118080);           // [4096][4096] fp32
  unsigned short* P   = (unsigned short*)(ws + 118226944); // [4096][4096] bf16
  // Split-K partials [8][4096][256] fp32 = 32MB: reuse lg (consumed by then).
  float*          pvp = lg;
  (void)ws_size; (void)in_sizes; (void)n_in; (void)out_size;

  const dim3 B256(256);
  const long S = 1048576;  // 4096*256 (= 256*4096) element batch stride

  convert6<<<1536, B256, 0, stream>>>(wq, wk, wv, wo, w1, w2, wqb);
  embed_k<<<4096, B256, 0, stream>>>(emb);
  // pe MLP: h1 = silu(embed @ w1^T + b1); peF = h1 @ w2^T + b2  (fp32 out)
  gemm_nt<1, 2, 0, 1><<<dim3(32, 2, 1), B256, 0, stream>>>(
      emb, w1b, h1b, 256, 256, 256, 0, 0, 0, b1, nullptr, 1.0f);
  gemm_nt<0, 2, 0, 0><<<dim3(32, 2, 1), B256, 0, stream>>>(
      h1b, w2b, peF, 256, 256, 256, 0, 0, 0, b2, nullptr, 1.0f);
  transpose_x<<<dim3(128, 8, 4), dim3(32, 8), 0, stream>>>(x, XT);
  // qT[s,o] = XT.wq + bq[o] + pe[o*4096+s]   (pe mode 2: col-major index)
  gemm_nt<1, 2, 2, 0><<<dim3(32, 2, 4), B256, 0, stream>>>(
      XT, wqb, qT, 256, 256, 256, S, 0, S, bq, peF, 1.0f);
  gemm_nt<1, 2, 2, 0><<<dim3(32, 2, 4), B256, 0, stream>>>(
      XT, wkb, kT, 256, 256, 256, S, 0, S, bk, peF, 1.0f);
  // v[o,s] = wv.XT + bv[o] + pe[o*4096+s]    (pe mode 1: row-major index)
  gemm_nt<1, 1, 1, 0><<<dim3(2, 32, 4), B256, 0, stream>>>(
      wvb, XT, vB, 256, 4096, 256, 0, S, S, bv, peF, 1.0f);

  for (int b = 0; b < 4; ++b) {
    // logitsT[j,i] = kT[j].qT[i] / 16  (fp32)
    gemm_nt<0, 0, 0, 0><<<dim3(32, 32, 1), B256, 0, stream>>>(
        kT + (long)b * S, qT + (long)b * S, lg, 256, 4096, 256, 0, 0, 0,
        nullptr, nullptr, 0.0625f);
    softmax_rows<<<4096, B256, 0, stream>>>(lg, P);
    // resT[j,c] partials: split-K=8, chunk 512, z = split index.
    // sA=sB=512: per-split k-offset; sC=1M: per-split partial plane.
    gemm_nt<0, 0, 0, 0><<<dim3(32, 2, 8), B256, 0, stream>>>(
        P, vB + (long)b * S, pvp, 512, 256, 4096, 512, 512, S,
        nullptr, nullptr, 1.0f);
    reduce8<<<1024, B256, 0, stream>>>(pvp, rT + (long)b * S);
  }
  // out[o,s] = wout . resT + b_out[o]  (fp32 -> d_out)
  gemm_nt<0, 1, 0, 0><<<dim3(2, 32, 4), B256, 0, stream>>>(
      wob, rT, out, 256, 4096, 256, 0, S, S, bo, nullptr, 1.0f);
}

// Round 4
// 282.437 us; speedup vs baseline: 2.0168x; 1.1826x over previous
//
#include <hip/hip_runtime.h>
#include <cstdint>

// ---------------------------------------------------------------------------
// SAGAN self-attention block, bf16-MFMA pipeline, flash-fused attention.
// GEMMs are NT form: C[m,n] = sum_k Arow[m][k] * Brow[n][k].
// Verified fragment conventions (R2-passing gemm):
//   A-frag: lane holds A[row = lane&15][k = (lane>>4)*8 + q], q=0..7
//   B-frag: lane holds B[col = lane&15][k = (lane>>4)*8 + q]
//   C/D:    lane holds C[row = (lane>>4)*4 + r][col = lane&15], r=0..3
// ---------------------------------------------------------------------------

typedef short s8v __attribute__((ext_vector_type(8)));   // 8 bf16 bits (4 VGPR)
typedef float f32x4 __attribute__((ext_vector_type(4)));

#define DEVI static __device__ __forceinline__

DEVI unsigned short f2bf(float f) {
  union { float f; uint32_t u; } x; x.f = f;
  uint32_t u = x.u;
  return (unsigned short)((u + 0x7fffu + ((u >> 16) & 1u)) >> 16);  // RNE
}

DEVI void gl_lds16(const void* g, void* l) {
  // async global->LDS, 16B per lane; LDS dest must be wave-uniform base.
  __builtin_amdgcn_global_load_lds(
      (const __attribute__((address_space(1))) void*)g,
      (__attribute__((address_space(3))) void*)l,
      16, 0, 0);
}

// Stage a [64 rows][32 k] bf16 tile (4KB) with all 256 threads.
// src points at (row0, k0); lds gets row-major [64][32].
DEVI void stage(const unsigned short* src, int ld, unsigned short* lds, int t) {
  gl_lds16(src + (long)(t >> 2) * ld + (t & 3) * 8, lds + (t >> 6) * 512);
}

// ---------------------------------------------------------------------------
// NT GEMM: 128x128 tile, 4 waves (2x2), each wave 64x64 = 4x4 frags of
// 16x16x32 bf16 MFMA. Epilogue templated:
//   OBF: 1 -> bf16 out, 0 -> fp32 out
//   BIAS: 0 none, 1 bias[row(m)], 2 bias[col(n)]
//   PEM:  0 none, 1 +pe[row*4096+col], 2 +pe[col*4096+row]
//   SILU: apply x*sigmoid(x)
// K = k-loop length; ld = row stride of A and B.
// ---------------------------------------------------------------------------
template <int OBF, int BIAS, int PEM, int SILU>
__global__ __launch_bounds__(256) void gemm_nt(
    const unsigned short* __restrict__ A, const unsigned short* __restrict__ B,
    void* __restrict__ Cp, int K, int N, int ld, long sA, long sB, long sC,
    const float* __restrict__ bias, const float* __restrict__ pe, float scale) {
  const int bz = blockIdx.z;
  const unsigned short* Ab = A + (long)bz * sA;
  const unsigned short* Bb = B + (long)bz * sB;
  const int m0 = blockIdx.x * 128, n0 = blockIdx.y * 128;
  __shared__ __align__(16) unsigned short As[4096], Bs[4096];  // [128][32]
  const int t = threadIdx.x;
  const int wave = t >> 6, lane = t & 63;
  const int wr = wave >> 1, wc = wave & 1;

  f32x4 acc[4][4];
#pragma unroll
  for (int i = 0; i < 4; i++)
#pragma unroll
    for (int j = 0; j < 4; j++) acc[i][j] = f32x4{0.f, 0.f, 0.f, 0.f};

  const int rl = lane & 15, kp = (lane >> 4) * 8;

  for (int k0 = 0; k0 < K; k0 += 32) {
    stage(Ab + (long)m0 * ld + k0, ld, As, t);
    stage(Ab + (long)(m0 + 64) * ld + k0, ld, As + 2048, t);
    stage(Bb + (long)n0 * ld + k0, ld, Bs, t);
    stage(Bb + (long)(n0 + 64) * ld + k0, ld, Bs + 2048, t);
    __syncthreads();  // drains vmcnt before barrier -> LDS valid

    s8v af[4], bfr[4];
#pragma unroll
    for (int i = 0; i < 4; i++)
      af[i] = *(const s8v*)(As + (wr * 64 + i * 16 + rl) * 32 + kp);
#pragma unroll
    for (int j = 0; j < 4; j++)
      bfr[j] = *(const s8v*)(Bs + (wc * 64 + j * 16 + rl) * 32 + kp);
#pragma unroll
    for (int i = 0; i < 4; i++)
#pragma unroll
      for (int j = 0; j < 4; j++)
        acc[i][j] = __builtin_amdgcn_mfma_f32_16x16x32_bf16(af[i], bfr[j],
                                                            acc[i][j], 0, 0, 0);
    __syncthreads();
  }

  const long cb = (long)bz * sC;
#pragma unroll
  for (int i = 0; i < 4; i++) {
    const int r0 = m0 + wr * 64 + i * 16 + (lane >> 4) * 4;
#pragma unroll
    for (int j = 0; j < 4; j++) {
      const int col = n0 + wc * 64 + j * 16 + (lane & 15);
#pragma unroll
      for (int r = 0; r < 4; r++) {
        const int row = r0 + r;
        float val = acc[i][j][r] * scale;
        if (BIAS == 1) val += bias[row];
        if (BIAS == 2) val += bias[col];
        if (PEM == 1) val += pe[(long)row * 4096 + col];
        if (PEM == 2) val += pe[(long)col * 4096 + row];
        if (SILU) val = val / (1.0f + __expf(-val));
        const long ci = cb + (long)row * N + col;
        if (OBF)
          ((unsigned short*)Cp)[ci] = f2bf(val);
        else
          ((float*)Cp)[ci] = val;
      }
    }
  }
}

// ---------------------------------------------------------------------------
// Flash-fused attention: per block, 64 j-rows of one batch; full i-loop with
// online softmax over i; O[64 j][256 c] accumulated in registers.
// logitsT[j,i] = kT[j].qT[i]/16; P = softmax_i; O[j,c] = sum_i P[j,i] v[c,i].
// ---------------------------------------------------------------------------
__global__ __launch_bounds__(256) void flash_attn(
    const unsigned short* __restrict__ qTp, const unsigned short* __restrict__ kTp,
    const unsigned short* __restrict__ vBp, unsigned short* __restrict__ rTp) {
  const int bid = blockIdx.x;
  // XCD-aware mapping (perf heuristic only): 2 XCDs per batch -> per-XCD L2
  // working set = one batch's qT+vB = 4MB (fits 4MB XCD L2).
  const int xcd = bid & 7;
  const int b = xcd >> 1;
  const int j0 = ((bid >> 3) + (xcd & 1) * 32) * 64;
  const long S = 1048576;
  const unsigned short* q = qTp + (long)b * S;
  const unsigned short* k = kTp + (long)b * S;
  const unsigned short* v = vBp + (long)b * S;
  unsigned short* rT = rTp + (long)b * S;

  __shared__ __align__(16) unsigned short kL[16384];  // [8 ks][64 j][32]
  __shared__ __align__(16) unsigned short qL[16384];  // [8 ks][64 i][32]
  __shared__ __align__(16) unsigned short vL[16384];  // [4 cg][2 ki][64 c][32 i]
  __shared__ __align__(16) unsigned short pL[4096];   // [4 w][2 ki][16 j][32 i]

  const int t = threadIdx.x, wave = t >> 6, lane = t & 63;
  const int rl = lane & 15, kp = (lane >> 4) * 8;

  // K strip [64 j][256] staged once, lives whole kernel.
#pragma unroll
  for (int s = 0; s < 8; s++)
    stage(k + (long)j0 * 256 + s * 32, 256, kL + s * 2048, t);

  f32x4 oacc[16];
#pragma unroll
  for (int f = 0; f < 16; f++) oacc[f] = f32x4{0.f, 0.f, 0.f, 0.f};
  float m[4], lsum[4];
#pragma unroll
  for (int r = 0; r < 4; r++) { m[r] = -1e30f; lsum[r] = 0.f; }

  for (int it = 0; it < 64; ++it) {
    const int i0 = it * 64;
    __syncthreads();  // all waves done reading previous qL/vL
#pragma unroll
    for (int s = 0; s < 8; s++)
      stage(q + (long)i0 * 256 + s * 32, 256, qL + s * 2048, t);
#pragma unroll
    for (int g = 0; g < 4; g++)
#pragma unroll
      for (int ki = 0; ki < 2; ki++)
        stage(v + (long)(g * 64) * 4096 + i0 + ki * 32, 4096,
              vL + g * 4096 + ki * 2048, t);
    __syncthreads();  // staging (vmcnt) drained

    // QK^T: wave's 16-j strip x 64 i. A = kT rows (m=j), B = qT rows (n=i).
    f32x4 sa[4];
#pragma unroll
    for (int f = 0; f < 4; f++) sa[f] = f32x4{0.f, 0.f, 0.f, 0.f};
#pragma unroll
    for (int s = 0; s < 8; s++) {
      s8v af = *(const s8v*)(kL + s * 2048 + (wave * 16 + rl) * 32 + kp);
#pragma unroll
      for (int f = 0; f < 4; f++) {
        s8v bf = *(const s8v*)(qL + s * 2048 + (f * 16 + rl) * 32 + kp);
        sa[f] = __builtin_amdgcn_mfma_f32_16x16x32_bf16(af, bf, sa[f], 0, 0, 0);
      }
    }

    // Online softmax over i. Row r holds j = j0 + wave*16 + (lane>>4)*4 + r;
    // i values for that row live in 4 frags x 16 lanes (l&15).
    float corr[4], pv[4][4];  // pv[f][r]
#pragma unroll
    for (int r = 0; r < 4; r++) {
      float tm = fmaxf(fmaxf(sa[0][r], sa[1][r]), fmaxf(sa[2][r], sa[3][r])) *
                 0.0625f;
      tm = fmaxf(tm, __shfl_xor(tm, 1));
      tm = fmaxf(tm, __shfl_xor(tm, 2));
      tm = fmaxf(tm, __shfl_xor(tm, 4));
      tm = fmaxf(tm, __shfl_xor(tm, 8));
      const float mn = fmaxf(m[r], tm);
      corr[r] = __expf(m[r] - mn);
      m[r] = mn;
      float ps = 0.f;
#pragma unroll
      for (int f = 0; f < 4; f++) {
        const float p = __expf(sa[f][r] * 0.0625f - mn);
        pv[f][r] = p;
        ps += p;
      }
      ps += __shfl_xor(ps, 1);
      ps += __shfl_xor(ps, 2);
      ps += __shfl_xor(ps, 4);
      ps += __shfl_xor(ps, 8);
      lsum[r] = lsum[r] * corr[r] + ps;
    }
    // Rescale O by corr (per accumulator row r).
#pragma unroll
    for (int f2 = 0; f2 < 16; f2++)
#pragma unroll
      for (int r = 0; r < 4; r++) oacc[f2][r] *= corr[r];

    // P -> LDS in A-fragment layout: pL[w][ki=f>>1][j_local][i_in_32].
#pragma unroll
    for (int f = 0; f < 4; f++)
#pragma unroll
      for (int r = 0; r < 4; r++)
        pL[wave * 1024 + (f >> 1) * 512 + ((lane >> 4) * 4 + r) * 32 +
           (f & 1) * 16 + rl] = f2bf(pv[f][r]);

    // PV: O[16 j][256 c] += P[16 j][64 i] * V[c][i-tile].
#pragma unroll
    for (int ki = 0; ki < 2; ki++) {
      s8v pa = *(const s8v*)(pL + wave * 1024 + ki * 512 + rl * 32 + kp);
#pragma unroll
      for (int f2 = 0; f2 < 16; f2++) {
        s8v vb = *(const s8v*)(vL + (f2 >> 2) * 4096 + ki * 2048 +
                               ((f2 & 3) * 16 + rl) * 32 + kp);
        oacc[f2] = __builtin_amdgcn_mfma_f32_16x16x32_bf16(pa, vb, oacc[f2],
                                                           0, 0, 0);
      }
    }
  }

  // Epilogue: normalize by lsum, write rT[j][c] bf16.
  float inv[4];
#pragma unroll
  for (int r = 0; r < 4; r++) inv[r] = 1.0f / lsum[r];
#pragma unroll
  for (int f2 = 0; f2 < 16; f2++) {
    const int c = f2 * 16 + rl;
#pragma unroll
    for (int r = 0; r < 4; r++) {
      const int j = j0 + wave * 16 + (lane >> 4) * 4 + r;
      rT[(long)j * 256 + c] = f2bf(oacc[f2][r] * inv[r]);
    }
  }
}

// Convert the six 256x256 fp32 weight matrices to bf16 (contiguous dst).
__global__ __launch_bounds__(256) void convert6(
    const float* __restrict__ a0, const float* __restrict__ a1,
    const float* __restrict__ a2, const float* __restrict__ a3,
    const float* __restrict__ a4, const float* __restrict__ a5,
    unsigned short* __restrict__ dst) {
  int idx = blockIdx.x * 256 + threadIdx.x;
  int m = idx >> 16, r = idx & 65535;
  const float* s;
  switch (m) {
    case 0: s = a0; break;
    case 1: s = a1; break;
    case 2: s = a2; break;
    case 3: s = a3; break;
    case 4: s = a4; break;
    default: s = a5; break;
  }
  dst[idx] = f2bf(s[r]);
}

// Sinusoidal table: embed[t,d] = sin/cos(t * 10000^(-d/128)), d even->sin.
__global__ __launch_bounds__(256) void embed_k(unsigned short* __restrict__ e) {
  int idx = blockIdx.x * 256 + threadIdx.x;
  int t = idx >> 8, d = idx & 255;
  float freq = powf(10000.0f, -(float)d * (1.0f / 128.0f));
  float w = (float)t * freq;
  float r = (d & 1) ? cosf(w) : sinf(w);
  e[idx] = f2bf(r);
}

// x [4][256][4096] fp32  ->  XT [4][4096][256] bf16
__global__ void transpose_x(const float* __restrict__ x,
                            unsigned short* __restrict__ xt) {
  __shared__ float tile[32][33];
  const int b = blockIdx.z;
  const int s0 = blockIdx.x * 32, c0 = blockIdx.y * 32;
  const int tx = threadIdx.x, ty = threadIdx.y;
  const float* xb = x + (long)b * 256 * 4096;
#pragma unroll
  for (int r = 0; r < 32; r += 8)
    tile[ty + r][tx] = xb[(long)(c0 + ty + r) * 4096 + s0 + tx];
  __syncthreads();
  unsigned short* xtb = xt + (long)b * 4096 * 256;
#pragma unroll
  for (int r = 0; r < 32; r += 8)
    xtb[(long)(s0 + ty + r) * 256 + c0 + tx] = f2bf(tile[tx][ty + r]);
}

// ---------------------------------------------------------------------------
extern "C" void kernel_launch(void* const* d_in, const int* in_sizes, int n_in,
                              void* d_out, int out_size, void* d_ws,
                              size_t ws_size, hipStream_t stream) {
  const float* x  = (const float*)d_in[0];
  const float* wq = (const float*)d_in[1];
  const float* bq = (const float*)d_in[2];
  const float* wk = (const float*)d_in[3];
  const float* bk = (const float*)d_in[4];
  const float* wv = (const float*)d_in[5];
  const float* bv = (const float*)d_in[6];
  const float* wo = (const float*)d_in[7];
  const float* bo = (const float*)d_in[8];
  const float* w1 = (const float*)d_in[9];
  const float* b1 = (const float*)d_in[10];
  const float* w2 = (const float*)d_in[11];
  const float* b2 = (const float*)d_in[12];
  float* out = (float*)d_out;

  char* ws = (char*)d_ws;
  unsigned short* wqb = (unsigned short*)(ws + 0);         // 6x 256x256 bf16
  unsigned short* wkb = (unsigned short*)(ws + 131072);
  unsigned short* wvb = (unsigned short*)(ws + 262144);
  unsigned short* wob = (unsigned short*)(ws + 393216);
  unsigned short* w1b = (unsigned short*)(ws + 524288);
  unsigned short* w2b = (unsigned short*)(ws + 655360);
  unsigned short* emb = (unsigned short*)(ws + 786432);    // [4096][256] bf16
  unsigned short* h1b = (unsigned short*)(ws + 2883584);   // [4096][256] bf16
  float*          peF = (float*)(ws + 4980736);            // [4096][256] fp32
  unsigned short* XT  = (unsigned short*)(ws + 9175040);   // [4][4096][256]
  unsigned short* qT  = (unsigned short*)(ws + 17563648);  // [4][4096][256]
  unsigned short* kT  = (unsigned short*)(ws + 25952256);  // [4][4096][256]
  unsigned short* vB  = (unsigned short*)(ws + 34340864);  // [4][256][4096]
  unsigned short* rT  = (unsigned short*)(ws + 42729472);  // [4][4096][256]
  (void)ws_size; (void)in_sizes; (void)n_in; (void)out_size;

  const dim3 B256(256);
  const long S = 1048576;  // 4096*256 (= 256*4096) element batch stride

  convert6<<<1536, B256, 0, stream>>>(wq, wk, wv, wo, w1, w2, wqb);
  embed_k<<<4096, B256, 0, stream>>>(emb);
  // pe MLP: h1 = silu(embed @ w1^T + b1); peF = h1 @ w2^T + b2  (fp32 out)
  gemm_nt<1, 2, 0, 1><<<dim3(32, 2, 1), B256, 0, stream>>>(
      emb, w1b, h1b, 256, 256, 256, 0, 0, 0, b1, nullptr, 1.0f);
  gemm_nt<0, 2, 0, 0><<<dim3(32, 2, 1), B256, 0, stream>>>(
      h1b, w2b, peF, 256, 256, 256, 0, 0, 0, b2, nullptr, 1.0f);
  transpose_x<<<dim3(128, 8, 4), dim3(32, 8), 0, stream>>>(x, XT);
  // qT[s,o] = XT.wq + bq[o] + pe[o*4096+s]   (pe mode 2: col-major index)
  gemm_nt<1, 2, 2, 0><<<dim3(32, 2, 4), B256, 0, stream>>>(
      XT, wqb, qT, 256, 256, 256, S, 0, S, bq, peF, 1.0f);
  gemm_nt<1, 2, 2, 0><<<dim3(32, 2, 4), B256, 0, stream>>>(
      XT, wkb, kT, 256, 256, 256, S, 0, S, bk, peF, 1.0f);
  // v[o,s] = wv.XT + bv[o] + pe[o*4096+s]    (pe mode 1: row-major index)
  gemm_nt<1, 1, 1, 0><<<dim3(2, 32, 4), B256, 0, stream>>>(
      wvb, XT, vB, 256, 4096, 256, 0, S, S, bv, peF, 1.0f);

  // Fused attention: logits + softmax(axis i) + PV, no HBM intermediates.
  flash_attn<<<256, B256, 0, stream>>>(qT, kT, vB, rT);

  // out[o,s] = wout . resT + b_out[o]  (fp32 -> d_out)
  gemm_nt<0, 1, 0, 0><<<dim3(2, 32, 4), B256, 0, stream>>>(
      wob, rT, out, 256, 4096, 256, 0, S, S, bo, nullptr, 1.0f);
}

// Round 5
// 209.972 us; speedup vs baseline: 2.7128x; 1.3451x over previous
//
#include <hip/hip_runtime.h>
#include <cstdint>

// ---------------------------------------------------------------------------
// SAGAN self-attention block, bf16-MFMA pipeline, flash-fused attention.
// GEMMs are NT form: C[m,n] = sum_k Arow[m][k] * Brow[n][k].
// Verified fragment conventions (R2-passing gemm):
//   A-frag: lane holds A[row = lane&15][k = (lane>>4)*8 + q], q=0..7
//   B-frag: lane holds B[col = lane&15][k = (lane>>4)*8 + q]
//   C/D:    lane holds C[row = (lane>>4)*4 + r][col = lane&15], r=0..3
// ---------------------------------------------------------------------------

typedef short s8v __attribute__((ext_vector_type(8)));   // 8 bf16 bits (4 VGPR)
typedef float f32x4 __attribute__((ext_vector_type(4)));

#define DEVI static __device__ __forceinline__

DEVI unsigned short f2bf(float f) {
  union { float f; uint32_t u; } x; x.f = f;
  uint32_t u = x.u;
  return (unsigned short)((u + 0x7fffu + ((u >> 16) & 1u)) >> 16);  // RNE
}

DEVI void gl_lds16(const void* g, void* l) {
  // async global->LDS, 16B per lane; LDS dest must be wave-uniform base.
  __builtin_amdgcn_global_load_lds(
      (const __attribute__((address_space(1))) void*)g,
      (__attribute__((address_space(3))) void*)l,
      16, 0, 0);
}

// Stage a [64 rows][32 k] bf16 tile (4KB), linear LDS layout (gemm_nt).
DEVI void stage(const unsigned short* src, int ld, unsigned short* lds, int t) {
  gl_lds16(src + (long)(t >> 2) * ld + (t & 3) * 8, lds + (t >> 6) * 512);
}

// Swizzled stage: LDS slot (row, chunk c) holds global chunk c ^ ((row>>1)&3).
// Achieved by pre-swizzling the per-lane GLOBAL source (LDS dest stays linear,
// as global_load_lds requires). Readers use ksw = ((lane>>4)^((rl>>1)&3))<<3.
DEVI void stage_s(const unsigned short* src, int ld, unsigned short* lds,
                  int tt) {
  const int tr = tt >> 2, c = tt & 3;
  const int sc = (c ^ ((tr >> 1) & 3)) * 8;
  gl_lds16(src + (long)tr * ld + sc, lds + (tt >> 6) * 512);
}

// ---------------------------------------------------------------------------
// NT GEMM: 128x128 tile, 4 waves (2x2), each wave 64x64 = 4x4 frags of
// 16x16x32 bf16 MFMA. (Unchanged from R2/R3 passing version.)
// ---------------------------------------------------------------------------
template <int OBF, int BIAS, int PEM, int SILU>
__global__ __launch_bounds__(256) void gemm_nt(
    const unsigned short* __restrict__ A, const unsigned short* __restrict__ B,
    void* __restrict__ Cp, int K, int N, int ld, long sA, long sB, long sC,
    const float* __restrict__ bias, const float* __restrict__ pe, float scale) {
  const int bz = blockIdx.z;
  const unsigned short* Ab = A + (long)bz * sA;
  const unsigned short* Bb = B + (long)bz * sB;
  const int m0 = blockIdx.x * 128, n0 = blockIdx.y * 128;
  __shared__ __align__(16) unsigned short As[4096], Bs[4096];  // [128][32]
  const int t = threadIdx.x;
  const int wave = t >> 6, lane = t & 63;
  const int wr = wave >> 1, wc = wave & 1;

  f32x4 acc[4][4];
#pragma unroll
  for (int i = 0; i < 4; i++)
#pragma unroll
    for (int j = 0; j < 4; j++) acc[i][j] = f32x4{0.f, 0.f, 0.f, 0.f};

  const int rl = lane & 15, kp = (lane >> 4) * 8;

  for (int k0 = 0; k0 < K; k0 += 32) {
    stage(Ab + (long)m0 * ld + k0, ld, As, t);
    stage(Ab + (long)(m0 + 64) * ld + k0, ld, As + 2048, t);
    stage(Bb + (long)n0 * ld + k0, ld, Bs, t);
    stage(Bb + (long)(n0 + 64) * ld + k0, ld, Bs + 2048, t);
    __syncthreads();  // drains vmcnt before barrier -> LDS valid

    s8v af[4], bfr[4];
#pragma unroll
    for (int i = 0; i < 4; i++)
      af[i] = *(const s8v*)(As + (wr * 64 + i * 16 + rl) * 32 + kp);
#pragma unroll
    for (int j = 0; j < 4; j++)
      bfr[j] = *(const s8v*)(Bs + (wc * 64 + j * 16 + rl) * 32 + kp);
#pragma unroll
    for (int i = 0; i < 4; i++)
#pragma unroll
      for (int j = 0; j < 4; j++)
        acc[i][j] = __builtin_amdgcn_mfma_f32_16x16x32_bf16(af[i], bfr[j],
                                                            acc[i][j], 0, 0, 0);
    __syncthreads();
  }

  const long cb = (long)bz * sC;
#pragma unroll
  for (int i = 0; i < 4; i++) {
    const int r0 = m0 + wr * 64 + i * 16 + (lane >> 4) * 4;
#pragma unroll
    for (int j = 0; j < 4; j++) {
      const int col = n0 + wc * 64 + j * 16 + (lane & 15);
#pragma unroll
      for (int r = 0; r < 4; r++) {
        const int row = r0 + r;
        float val = acc[i][j][r] * scale;
        if (BIAS == 1) val += bias[row];
        if (BIAS == 2) val += bias[col];
        if (PEM == 1) val += pe[(long)row * 4096 + col];
        if (PEM == 2) val += pe[(long)col * 4096 + row];
        if (SILU) val = val / (1.0f + __expf(-val));
        const long ci = cb + (long)row * N + col;
        if (OBF)
          ((unsigned short*)Cp)[ci] = f2bf(val);
        else
          ((float*)Cp)[ci] = val;
      }
    }
  }
}

// ---------------------------------------------------------------------------
// Flash-fused attention v2: 512 threads = 8 waves = (h in 0..2) x (w in 0..4).
// Block owns 64 j-rows; full i-loop (64 tiles of 64). Static-max softmax
// (|logit| << 88 -> exp in fp32 is safe without max subtraction), so halves
// are independent: half h computes QK i-frags [h*32,h*32+32) and PV c-cols
// [h*128,h*128+128); only lsum is merged at the end.
// K-strip lives in registers (each wave reads only its own 16 j-rows).
// qL/vL double-buffered, chunk-XOR swizzled (conflict fix); pL per-wave/ki.
// ---------------------------------------------------------------------------
__global__ __launch_bounds__(512, 2) void flash_attn(
    const unsigned short* __restrict__ qTp, const unsigned short* __restrict__ kTp,
    const unsigned short* __restrict__ vBp, unsigned short* __restrict__ rTp) {
  const int bid = blockIdx.x;
  // XCD-aware mapping (perf heuristic only): 2 XCDs per batch -> per-XCD L2
  // working set = one batch's qT+vB = 4MB (fits 4MB XCD L2).
  const int xcd = bid & 7;
  const int b = xcd >> 1;
  const int j0 = ((bid >> 3) + (xcd & 1) * 32) * 64;
  const long S = 1048576;
  const unsigned short* q = qTp + (long)b * S;
  const unsigned short* k = kTp + (long)b * S;
  const unsigned short* v = vBp + (long)b * S;
  unsigned short* rT = rTp + (long)b * S;

  __shared__ __align__(16) unsigned short qL[2][16384];  // [buf][8s][64 i][32]
  __shared__ __align__(16) unsigned short vL[2][16384];  // [buf][4cg][2ki][64c][32]
  __shared__ __align__(16) unsigned short pL[4096];      // [4w][2ki][16 j][32 i]

  const int t = threadIdx.x;
  const int wave = t >> 6, lane = t & 63;
  const int h = wave >> 2, w = wave & 3;
  const int rl = lane & 15;
  const int ksw = (((lane >> 4) ^ ((rl >> 1) & 3)) << 3);  // swizzled k-offset
  const int th = t >> 8, tt = t & 255;                     // staging split

  // K-strip -> registers: wave (h,w) only ever needs rows j0 + w*16 + rl.
  const unsigned short* krow = k + (long)(j0 + w * 16 + rl) * 256 +
                               (lane >> 4) * 8;
  s8v kreg[8];
#pragma unroll
  for (int s = 0; s < 8; s++) kreg[s] = *(const s8v*)(krow + s * 32);

  f32x4 oacc[8];
#pragma unroll
  for (int f = 0; f < 8; f++) oacc[f] = f32x4{0.f, 0.f, 0.f, 0.f};
  float lsum[4] = {0.f, 0.f, 0.f, 0.f};

  // Stage (qL,vL) for i-tile `it` into buffer `bf`: 16 x 4KB tiles, 512 thr.
#define STAGE_QV(it, bf)                                                     \
  {                                                                          \
    const long i0_ = (long)(it) * 64;                                        \
    _Pragma("unroll") for (int ss = 0; ss < 4; ss++) {                       \
      const int s_ = ss * 2 + th;                                            \
      stage_s(q + i0_ * 256 + s_ * 32, 256, qL[bf] + s_ * 2048, tt);         \
    }                                                                        \
    _Pragma("unroll") for (int ss = 0; ss < 4; ss++) {                       \
      const int vt_ = ss * 2 + th;                                           \
      stage_s(v + (long)((vt_ >> 1) * 64) * 4096 + i0_ + (vt_ & 1) * 32,     \
              4096, vL[bf] + vt_ * 2048, tt);                                \
    }                                                                        \
  }

  STAGE_QV(0, 0)

  for (int n = 0; n < 64; ++n) {
    const int cur = n & 1;
    __syncthreads();  // staged buf[cur] ready; prev iter's pL fully consumed
    if (n + 1 < 64) STAGE_QV(n + 1, cur ^ 1)  // in flight during compute

    // QK^T: sa[f] covers i-cols (2h+f)*16 + rl of this tile.
    f32x4 sa[2];
    sa[0] = f32x4{0.f, 0.f, 0.f, 0.f};
    sa[1] = f32x4{0.f, 0.f, 0.f, 0.f};
    const int R0 = (2 * h) * 16 + rl, R1 = (2 * h + 1) * 16 + rl;
#pragma unroll
    for (int s = 0; s < 8; s++) {
      const unsigned short* qb = qL[cur] + s * 2048;
      s8v bf0 = *(const s8v*)(qb + R0 * 32 + ksw);
      s8v bf1 = *(const s8v*)(qb + R1 * 32 + ksw);
      sa[0] = __builtin_amdgcn_mfma_f32_16x16x32_bf16(kreg[s], bf0, sa[0], 0, 0, 0);
      sa[1] = __builtin_amdgcn_mfma_f32_16x16x32_bf16(kreg[s], bf1, sa[1], 0, 0, 0);
    }

    // Static-max softmax: P = exp(s/16); accumulate partial row sums.
#pragma unroll
    for (int r = 0; r < 4; r++) {
      const float p0 = __expf(sa[0][r] * 0.0625f);
      const float p1 = __expf(sa[1][r] * 0.0625f);
      float ps = p0 + p1;
      ps += __shfl_xor(ps, 1);
      ps += __shfl_xor(ps, 2);
      ps += __shfl_xor(ps, 4);
      ps += __shfl_xor(ps, 8);
      lsum[r] += ps;
      // pL write (swizzled): row j, ki = h, cols f*16+rl.
      const int j = (lane >> 4) * 4 + r;
      const int a0 = w * 1024 + h * 512 + j * 32 +
                     ((((rl >> 3) ^ ((j >> 1) & 3))) << 3) + (rl & 7);
      pL[a0] = f2bf(p0);
      pL[a0 ^ 16] = f2bf(p1);  // chunk xor 2 <=> elem offset xor 16
    }
    __syncthreads();  // pL visible across halves (also drains prefetch vmcnt)

    // PV: O[16 j][128 c-half] += P[16 j][64 i] * V.
#pragma unroll
    for (int ki = 0; ki < 2; ki++) {
      s8v pa = *(const s8v*)(pL + w * 1024 + ki * 512 + rl * 32 + ksw);
#pragma unroll
      for (int m = 0; m < 8; m++) {
        const int f2 = h * 8 + m;
        s8v vb = *(const s8v*)(vL[cur] + (f2 >> 2) * 4096 + ki * 2048 +
                               ((f2 & 3) * 16 + rl) * 32 + ksw);
        oacc[m] = __builtin_amdgcn_mfma_f32_16x16x32_bf16(pa, vb, oacc[m],
                                                          0, 0, 0);
      }
    }
  }

  // Merge lsum across halves (pL reused as 512 x float4 exchange buffer).
  __syncthreads();
  float4* xL = (float4*)pL;
  xL[wave * 64 + lane] = float4{lsum[0], lsum[1], lsum[2], lsum[3]};
  __syncthreads();
  const float4 ol = xL[(wave ^ 4) * 64 + lane];
  float inv[4];
  inv[0] = 1.0f / (lsum[0] + ol.x);
  inv[1] = 1.0f / (lsum[1] + ol.y);
  inv[2] = 1.0f / (lsum[2] + ol.z);
  inv[3] = 1.0f / (lsum[3] + ol.w);

#pragma unroll
  for (int m = 0; m < 8; m++) {
    const int c = (h * 8 + m) * 16 + rl;
#pragma unroll
    for (int r = 0; r < 4; r++) {
      const int j = j0 + w * 16 + (lane >> 4) * 4 + r;
      rT[(long)j * 256 + c] = f2bf(oacc[m][r] * inv[r]);
    }
  }
#undef STAGE_QV
}

// Convert the six 256x256 fp32 weight matrices to bf16 (contiguous dst).
__global__ __launch_bounds__(256) void convert6(
    const float* __restrict__ a0, const float* __restrict__ a1,
    const float* __restrict__ a2, const float* __restrict__ a3,
    const float* __restrict__ a4, const float* __restrict__ a5,
    unsigned short* __restrict__ dst) {
  int idx = blockIdx.x * 256 + threadIdx.x;
  int m = idx >> 16, r = idx & 65535;
  const float* s;
  switch (m) {
    case 0: s = a0; break;
    case 1: s = a1; break;
    case 2: s = a2; break;
    case 3: s = a3; break;
    case 4: s = a4; break;
    default: s = a5; break;
  }
  dst[idx] = f2bf(s[r]);
}

// Sinusoidal table: embed[t,d] = sin/cos(t * 10000^(-d/128)), d even->sin.
__global__ __launch_bounds__(256) void embed_k(unsigned short* __restrict__ e) {
  int idx = blockIdx.x * 256 + threadIdx.x;
  int t = idx >> 8, d = idx & 255;
  float freq = powf(10000.0f, -(float)d * (1.0f / 128.0f));
  float w = (float)t * freq;
  float r = (d & 1) ? cosf(w) : sinf(w);
  e[idx] = f2bf(r);
}

// x [4][256][4096] fp32  ->  XT [4][4096][256] bf16
__global__ void transpose_x(const float* __restrict__ x,
                            unsigned short* __restrict__ xt) {
  __shared__ float tile[32][33];
  const int b = blockIdx.z;
  const int s0 = blockIdx.x * 32, c0 = blockIdx.y * 32;
  const int tx = threadIdx.x, ty = threadIdx.y;
  const float* xb = x + (long)b * 256 * 4096;
#pragma unroll
  for (int r = 0; r < 32; r += 8)
    tile[ty + r][tx] = xb[(long)(c0 + ty + r) * 4096 + s0 + tx];
  __syncthreads();
  unsigned short* xtb = xt + (long)b * 4096 * 256;
#pragma unroll
  for (int r = 0; r < 32; r += 8)
    xtb[(long)(s0 + ty + r) * 256 + c0 + tx] = f2bf(tile[tx][ty + r]);
}

// ---------------------------------------------------------------------------
extern "C" void kernel_launch(void* const* d_in, const int* in_sizes, int n_in,
                              void* d_out, int out_size, void* d_ws,
                              size_t ws_size, hipStream_t stream) {
  const float* x  = (const float*)d_in[0];
  const float* wq = (const float*)d_in[1];
  const float* bq = (const float*)d_in[2];
  const float* wk = (const float*)d_in[3];
  const float* bk = (const float*)d_in[4];
  const float* wv = (const float*)d_in[5];
  const float* bv = (const float*)d_in[6];
  const float* wo = (const float*)d_in[7];
  const float* bo = (const float*)d_in[8];
  const float* w1 = (const float*)d_in[9];
  const float* b1 = (const float*)d_in[10];
  const float* w2 = (const float*)d_in[11];
  const float* b2 = (const float*)d_in[12];
  float* out = (float*)d_out;

  char* ws = (char*)d_ws;
  unsigned short* wqb = (unsigned short*)(ws + 0);         // 6x 256x256 bf16
  unsigned short* wkb = (unsigned short*)(ws + 131072);
  unsigned short* wvb = (unsigned short*)(ws + 262144);
  unsigned short* wob = (unsigned short*)(ws + 393216);
  unsigned short* w1b = (unsigned short*)(ws + 524288);
  unsigned short* w2b = (unsigned short*)(ws + 655360);
  unsigned short* emb = (unsigned short*)(ws + 786432);    // [4096][256] bf16
  unsigned short* h1b = (unsigned short*)(ws + 2883584);   // [4096][256] bf16
  float*          peF = (float*)(ws + 4980736);            // [4096][256] fp32
  unsigned short* XT  = (unsigned short*)(ws + 9175040);   // [4][4096][256]
  unsigned short* qT  = (unsigned short*)(ws + 17563648);  // [4][4096][256]
  unsigned short* kT  = (unsigned short*)(ws + 25952256);  // [4][4096][256]
  unsigned short* vB  = (unsigned short*)(ws + 34340864);  // [4][256][4096]
  unsigned short* rT  = (unsigned short*)(ws + 42729472);  // [4][4096][256]
  (void)ws_size; (void)in_sizes; (void)n_in; (void)out_size;

  const dim3 B256(256);
  const long S = 1048576;  // 4096*256 (= 256*4096) element batch stride

  convert6<<<1536, B256, 0, stream>>>(wq, wk, wv, wo, w1, w2, wqb);
  embed_k<<<4096, B256, 0, stream>>>(emb);
  // pe MLP: h1 = silu(embed @ w1^T + b1); peF = h1 @ w2^T + b2  (fp32 out)
  gemm_nt<1, 2, 0, 1><<<dim3(32, 2, 1), B256, 0, stream>>>(
      emb, w1b, h1b, 256, 256, 256, 0, 0, 0, b1, nullptr, 1.0f);
  gemm_nt<0, 2, 0, 0><<<dim3(32, 2, 1), B256, 0, stream>>>(
      h1b, w2b, peF, 256, 256, 256, 0, 0, 0, b2, nullptr, 1.0f);
  transpose_x<<<dim3(128, 8, 4), dim3(32, 8), 0, stream>>>(x, XT);
  // qT[s,o] = XT.wq + bq[o] + pe[o*4096+s]   (pe mode 2: col-major index)
  gemm_nt<1, 2, 2, 0><<<dim3(32, 2, 4), B256, 0, stream>>>(
      XT, wqb, qT, 256, 256, 256, S, 0, S, bq, peF, 1.0f);
  gemm_nt<1, 2, 2, 0><<<dim3(32, 2, 4), B256, 0, stream>>>(
      XT, wkb, kT, 256, 256, 256, S, 0, S, bk, peF, 1.0f);
  // v[o,s] = wv.XT + bv[o] + pe[o*4096+s]    (pe mode 1: row-major index)
  gemm_nt<1, 1, 1, 0><<<dim3(2, 32, 4), B256, 0, stream>>>(
      wvb, XT, vB, 256, 4096, 256, 0, S, S, bv, peF, 1.0f);

  // Fused attention: logits + softmax(axis i) + PV, no HBM intermediates.
  flash_attn<<<256, dim3(512), 0, stream>>>(qT, kT, vB, rT);

  // out[o,s] = wout . resT + b_out[o]  (fp32 -> d_out)
  gemm_nt<0, 1, 0, 0><<<dim3(2, 32, 4), B256, 0, stream>>>(
      wob, rT, out, 256, 4096, 256, 0, S, S, bo, nullptr, 1.0f);
}